// Round 1
// 361.091 us; speedup vs baseline: 1.1598x; 1.1598x over previous
//
#include <hip/hip_runtime.h>

#define NB 4
#define SEQ 4096
#define DM 1024
#define DF 64

typedef unsigned short u16;
typedef unsigned int u32;
typedef __attribute__((ext_vector_type(8))) short short8;   // 8 bf16 = 4 VGPR (MFMA A/B frag)
typedef __attribute__((ext_vector_type(4))) float f32x4;    // MFMA C/D frag

__device__ __forceinline__ float bf2f(u16 u) {
    union { u32 i; float f; } v; v.i = ((u32)u) << 16; return v.f;
}
__device__ __forceinline__ u16 f2bf(float f) {
    union { float f; u32 i; } v; v.f = f;
    u32 lsb = (v.i >> 16) & 1u;
    v.i += 0x7fffu + lsb;          // RNE
    return (u16)(v.i >> 16);
}

#define MFMA16(a, b, c) __builtin_amdgcn_mfma_f32_16x16x32_bf16(a, b, c, 0, 0, 0)

// ---------------- W prep: split fp32 W into bf16 hi/lo ----------------------
// 3 matrices x 64x1024. Whi[i]+Wlo[i] together carry ~16 mantissa bits.
__global__ __launch_bounds__(256) void wprep_kernel(
    const float* __restrict__ W0, const float* __restrict__ W1, const float* __restrict__ W2,
    u16* __restrict__ Whi, u16* __restrict__ Wlo)
{
    int i = blockIdx.x * 256 + threadIdx.x;            // 0 .. 3*65536-1
    const float* W = (i < 65536) ? W0 : (i < 131072) ? W1 : W2;
    float v = W[i & 65535];
    u16 hi = f2bf(v);
    Whi[i] = hi;
    Wlo[i] = f2bf(v - bf2f(hi));
}

// ---------------- Projection v3: split-bf16 MFMA GEMM -----------------------
// grid (1024, 3), block 256 (4 waves). Block owns 16 rows x 64 cols; wave w
// takes K-quarter [256w, 256w+256). 3 MFMAs per (N-tile, k-step):
//   x_hi*w_hi + x_lo*w_hi + x_hi*w_lo  (x_lo*w_lo ~ 2^-18, dropped).
// A-frag: A[m=lane&15][k=quad*8+j]; B-frag: B[k=quad*8+j][n=lane&15];
// D: col=lane&15, row=quad*4+reg  (same HW-verified layout as attention).
__global__ __launch_bounds__(256) void proj3_kernel(
    const float* __restrict__ X0, const float* __restrict__ X1, const float* __restrict__ X2,
    const u16* __restrict__ Whi, const u16* __restrict__ Wlo,
    const float* __restrict__ b0, const float* __restrict__ b1, const float* __restrict__ b2,
    u16* __restrict__ Oall)
{
    __shared__ float red[3][16 * 64];
    const int t    = threadIdx.x;
    const int w    = t >> 6;
    const int lane = t & 63;
    const int m15  = lane & 15;
    const int quad = lane >> 4;
    const int y    = blockIdx.y;

    const float* X    = (y == 0) ? X0 : (y == 1) ? X1 : X2;
    const float* bias = (y == 0) ? b0 : (y == 1) ? b1 : b2;
    const u16*   wh   = Whi + y * 65536;
    const u16*   wl   = Wlo + y * 65536;
    u16*         O    = Oall + (size_t)y * (NB * SEQ * DF);

    const long r0  = (long)blockIdx.x * 16;
    const long row = r0 + m15;
    const int kbase = w * 256 + quad * 8;     // this lane's k origin within its quarter

    f32x4 acc[4];
#pragma unroll
    for (int F = 0; F < 4; ++F) acc[F] = (f32x4){0.f, 0.f, 0.f, 0.f};

    const float* xp = X + row * DM + kbase;
    float4 xa0 = *(const float4*)(xp);
    float4 xa1 = *(const float4*)(xp + 4);

#pragma unroll
    for (int s = 0; s < 8; ++s) {             // 8 k-steps of 32
        const int k = kbase + 32 * s;
        float4 c0 = xa0, c1 = xa1;
        if (s + 1 < 8) {                      // prefetch next step (HBM latency hide)
            xa0 = *(const float4*)(xp + 32 * (s + 1));
            xa1 = *(const float4*)(xp + 32 * (s + 1) + 4);
        }
        float xs[8] = {c0.x, c0.y, c0.z, c0.w, c1.x, c1.y, c1.z, c1.w};
        short8 ahi, alo;
#pragma unroll
        for (int j = 0; j < 8; ++j) {
            u16 h = f2bf(xs[j]);
            ahi[j] = (short)h;
            alo[j] = (short)f2bf(xs[j] - bf2f(h));
        }
#pragma unroll
        for (int F = 0; F < 4; ++F) {
            short8 bhi = *(const short8*)(wh + (16 * F + m15) * DM + k);
            short8 blo = *(const short8*)(wl + (16 * F + m15) * DM + k);
            acc[F] = MFMA16(ahi, bhi, acc[F]);
            acc[F] = MFMA16(alo, bhi, acc[F]);
            acc[F] = MFMA16(ahi, blo, acc[F]);
        }
    }

    // cross-wave K-reduction through LDS
    if (w > 0) {
#pragma unroll
        for (int F = 0; F < 4; ++F)
#pragma unroll
            for (int r = 0; r < 4; ++r)
                red[w - 1][(4 * quad + r) * 64 + 16 * F + m15] = acc[F][r];
    }
    __syncthreads();
    if (w == 0) {
#pragma unroll
        for (int F = 0; F < 4; ++F) {
            float bv = bias[16 * F + m15];
#pragma unroll
            for (int r = 0; r < 4; ++r) {
                float v = acc[F][r] + bv;
#pragma unroll
                for (int g = 0; g < 3; ++g)
                    v += red[g][(4 * quad + r) * 64 + 16 * F + m15];
                O[(r0 + 4 * quad + r) * DF + 16 * F + m15] = f2bf(v);
            }
        }
    }
}

// ---------------- MFMA flash attention (key-split) --------------------------
// grid (64, NB, nsplit), block 256 (4 waves). Block covers 64 q rows; wave w
// owns q rows q0+16w..+15; blockIdx.z covers `ntiles` 64-key tiles.
// If norm==1 (nsplit==1): normalize in-kernel, write to Opart directly.
// Else: write unnormalized O + per-row (m,l) partials for the combine kernel.
#define KSTR 72          // padded LDS stride (shorts), keeps 16B align

__global__ __launch_bounds__(256) void attn_mfma_kernel(
    const u16* __restrict__ Qg, const u16* __restrict__ Kg, const u16* __restrict__ Vg,
    float* __restrict__ Opart, float* __restrict__ Mp, float* __restrict__ Lp,
    int ntiles, int norm)
{
    __shared__ u16 ks[64 * KSTR];        // K tile, row-major [key][d]
    __shared__ u16 vt[64 * KSTR];        // V tile TRANSPOSED [f][key]
    __shared__ u16 ps[4][16 * KSTR];     // per-wave P tile [q][key]

    const int t    = threadIdx.x;
    const int w    = t >> 6;
    const int lane = t & 63;
    const int m15  = lane & 15;
    const int quad = lane >> 4;
    const int b    = blockIdx.y;
    const int z    = blockIdx.z;
    const int q0   = blockIdx.x * 64;

    // Q fragments, resident for the whole kernel (direct from global, bf16)
    const u16* qptr = Qg + ((long)(b * SEQ + q0 + 16 * w + m15)) * DF + quad * 8;
    short8 qa0 = *(const short8*)qptr;          // d 0..31 chunk
    short8 qa1 = *(const short8*)(qptr + 32);   // d 32..63 chunk

    f32x4 accO[4];
#pragma unroll
    for (int F = 0; F < 4; ++F) accO[F] = (f32x4){0.f, 0.f, 0.f, 0.f};
    float mrow[4] = {-1e30f, -1e30f, -1e30f, -1e30f};
    float lrow[4] = {0.f, 0.f, 0.f, 0.f};

    const long kvbase = ((long)b * SEQ + (long)z * ntiles * 64) * DF;
    const ushort4* kb4 = (const ushort4*)(Kg + kvbase);
    const ushort4* vb4 = (const ushort4*)(Vg + kvbase);

    // staging registers (software pipeline: global->reg ahead, reg->LDS at top)
    ushort4 kreg[4], vreg[4];
    const int krow  = t >> 4;          // K staging: rows krow, krow+16,32,48
    const int kcol4 = t & 15;
    const int vj0   = (t & 15) * 4;    // V transpose: keys vj0..vj0+3
    const int vf0   = (t >> 4) * 4;    // features vf0..vf0+3
#pragma unroll
    for (int c = 0; c < 4; ++c) {
        kreg[c] = kb4[(krow + 16 * c) * 16 + kcol4];
        vreg[c] = vb4[(vj0 + c) * 16 + (vf0 >> 2)];
    }

    for (int tile = 0; tile < ntiles; ++tile) {
        __syncthreads();   // prior tile's LDS readers done
#pragma unroll
        for (int c = 0; c < 4; ++c)    // K: raw bf16 copy
            *(ushort4*)&ks[(krow + 16 * c) * KSTR + kcol4 * 4] = kreg[c];
        {                              // V: 4x4 in-register transpose
            ushort4 w0 = {vreg[0].x, vreg[1].x, vreg[2].x, vreg[3].x};
            ushort4 w1 = {vreg[0].y, vreg[1].y, vreg[2].y, vreg[3].y};
            ushort4 w2 = {vreg[0].z, vreg[1].z, vreg[2].z, vreg[3].z};
            ushort4 w3 = {vreg[0].w, vreg[1].w, vreg[2].w, vreg[3].w};
            *(ushort4*)&vt[(vf0 + 0) * KSTR + vj0] = w0;
            *(ushort4*)&vt[(vf0 + 1) * KSTR + vj0] = w1;
            *(ushort4*)&vt[(vf0 + 2) * KSTR + vj0] = w2;
            *(ushort4*)&vt[(vf0 + 3) * KSTR + vj0] = w3;
        }
        __syncthreads();   // staging visible

        if (tile + 1 < ntiles) {       // prefetch next tile (latency hidden by compute)
#pragma unroll
            for (int c = 0; c < 4; ++c) {
                kreg[c] = kb4[(tile + 1) * 1024 + (krow + 16 * c) * 16 + kcol4];
                vreg[c] = vb4[(tile + 1) * 1024 + (vj0 + c) * 16 + (vf0 >> 2)];
            }
        }

        // ---- QK^T: 4 key-subtiles x 2 d-chunks ----
        f32x4 S[4];
#pragma unroll
        for (int T = 0; T < 4; ++T) {
            const u16* kp = &ks[(16 * T + m15) * KSTR + quad * 8];
            short8 kb0 = *(const short8*)kp;
            short8 kb1 = *(const short8*)(kp + 32);
            S[T] = MFMA16(qa0, kb0, ((f32x4){0.f, 0.f, 0.f, 0.f}));
            S[T] = MFMA16(qa1, kb1, S[T]);
        }

        // ---- online softmax (rows 4*quad+r live in this quad) ----
        float mx[4], alpha[4], mn[4], psum[4];
#pragma unroll
        for (int T = 0; T < 4; ++T)
#pragma unroll
            for (int r = 0; r < 4; ++r) S[T][r] *= 0.125f;   // 1/sqrt(64)
#pragma unroll
        for (int r = 0; r < 4; ++r) {
            mx[r] = fmaxf(fmaxf(S[0][r], S[1][r]), fmaxf(S[2][r], S[3][r]));
#pragma unroll
            for (int s = 1; s < 16; s <<= 1) mx[r] = fmaxf(mx[r], __shfl_xor(mx[r], s));
            mn[r] = fmaxf(mrow[r], mx[r]);
            alpha[r] = __expf(mrow[r] - mn[r]);
            mrow[r] = mn[r];
            psum[r] = 0.f;
        }
#pragma unroll
        for (int T = 0; T < 4; ++T)
#pragma unroll
            for (int r = 0; r < 4; ++r) {
                float p = __expf(S[T][r] - mn[r]);
                psum[r] += p;
                ps[w][(4 * quad + r) * KSTR + 16 * T + m15] = f2bf(p);
            }
#pragma unroll
        for (int r = 0; r < 4; ++r) {
#pragma unroll
            for (int s = 1; s < 16; s <<= 1) psum[r] += __shfl_xor(psum[r], s);
            lrow[r] = lrow[r] * alpha[r] + psum[r];
        }
#pragma unroll
        for (int F = 0; F < 4; ++F)
#pragma unroll
            for (int r = 0; r < 4; ++r) accO[F][r] *= alpha[r];

        // ---- PV: A = P (same-wave region, no barrier needed), B = Vt ----
        const u16* pp = &ps[w][m15 * KSTR + quad * 8];
        short8 pa0 = *(const short8*)pp;          // keys 0..31
        short8 pa1 = *(const short8*)(pp + 32);   // keys 32..63
#pragma unroll
        for (int F = 0; F < 4; ++F) {
            const u16* vp = &vt[(16 * F + m15) * KSTR + quad * 8];
            short8 vb0 = *(const short8*)vp;
            short8 vb1 = *(const short8*)(vp + 32);
            accO[F] = MFMA16(pa0, vb0, accO[F]);
            accO[F] = MFMA16(pa1, vb1, accO[F]);
        }
    }

    // ---- epilogue ----
    const long rowbase = (long)b * SEQ + q0 + 16 * w;
    if (norm) {
        float il[4];
#pragma unroll
        for (int r = 0; r < 4; ++r) il[r] = 1.f / lrow[r];
#pragma unroll
        for (int F = 0; F < 4; ++F)
#pragma unroll
            for (int r = 0; r < 4; ++r)
                Opart[(rowbase + 4 * quad + r) * DF + 16 * F + m15] = accO[F][r] * il[r];
    } else {
        float* Og = Opart + (size_t)z * (NB * SEQ * DF);
#pragma unroll
        for (int F = 0; F < 4; ++F)
#pragma unroll
            for (int r = 0; r < 4; ++r)
                Og[(rowbase + 4 * quad + r) * DF + 16 * F + m15] = accO[F][r];
        if (m15 == 0) {
#pragma unroll
            for (int r = 0; r < 4; ++r) {
                long rg = (long)z * (NB * SEQ) + rowbase + 4 * quad + r;
                Mp[rg] = mrow[r];
                Lp[rg] = lrow[r];
            }
        }
    }
}

// ---------------- combine: merge key-split flash partials -------------------
// out[row][f] = sum_g O_g[row][f] * e^{m_g - M} / (sum_g l_g * e^{m_g - M})
// 65536 threads: 4 threads/row, 16 features each.
__global__ __launch_bounds__(256) void combine_kernel(
    const float* __restrict__ Opart, const float* __restrict__ Mp, const float* __restrict__ Lp,
    float* __restrict__ out, int nsplit)
{
    const int tg  = blockIdx.x * 256 + threadIdx.x;
    const int row = tg >> 2;
    const int f0  = (tg & 3) * 16;

    float m = -1e30f;
    for (int g = 0; g < nsplit; ++g) m = fmaxf(m, Mp[g * (NB * SEQ) + row]);

    float l = 0.f;
    float4 o[4];
#pragma unroll
    for (int i = 0; i < 4; ++i) o[i] = (float4){0.f, 0.f, 0.f, 0.f};

    for (int g = 0; g < nsplit; ++g) {
        float e = __expf(Mp[g * (NB * SEQ) + row] - m);
        l += Lp[g * (NB * SEQ) + row] * e;
        const float* Op = Opart + ((long)g * (NB * SEQ) + row) * DF + f0;
#pragma unroll
        for (int i = 0; i < 4; ++i) {
            float4 v = *(const float4*)(Op + 4 * i);
            o[i].x += v.x * e; o[i].y += v.y * e; o[i].z += v.z * e; o[i].w += v.w * e;
        }
    }
    const float inv = 1.f / l;
#pragma unroll
    for (int i = 0; i < 4; ++i) {
        float4 v = {o[i].x * inv, o[i].y * inv, o[i].z * inv, o[i].w * inv};
        *(float4*)(out + (long)row * DF + f0 + 4 * i) = v;
    }
}

extern "C" void kernel_launch(void* const* d_in, const int* in_sizes, int n_in,
                              void* d_out, int out_size, void* d_ws, size_t ws_size,
                              hipStream_t stream) {
    (void)in_sizes; (void)n_in; (void)out_size;

    const float* X[3]  = { (const float*)d_in[0], (const float*)d_in[1], (const float*)d_in[2] };
    const float* W[3]  = { (const float*)d_in[3], (const float*)d_in[5], (const float*)d_in[7] };
    const float* Bv[3] = { (const float*)d_in[4], (const float*)d_in[6], (const float*)d_in[8] };

    char* wsb = (char*)d_ws;
    // workspace layout (bytes):
    const size_t P_BYTES  = (size_t)3 * NB * SEQ * DF * 2;   // 6,291,456  (Q,K,V bf16)
    const size_t WH_BYTES = (size_t)3 * DF * DM * 2;         //   393,216  (Whi / Wlo each)
    const size_t ML_BYTES = (size_t)4 * NB * SEQ * 4;        //   262,144  (Mp / Lp each, max 4 splits)
    const size_t OP_BYTES = (size_t)NB * SEQ * DF * 4;       // 4,194,304  (per split)

    u16*   P   = (u16*)wsb;
    u16*   Whi = (u16*)(wsb + P_BYTES);
    u16*   Wlo = (u16*)(wsb + P_BYTES + WH_BYTES);
    float* Mp  = (float*)(wsb + P_BYTES + 2 * WH_BYTES);
    float* Lp  = (float*)(wsb + P_BYTES + 2 * WH_BYTES + ML_BYTES);
    float* Op  = (float*)(wsb + P_BYTES + 2 * WH_BYTES + 2 * ML_BYTES);
    const size_t base_need = P_BYTES + 2 * WH_BYTES + 2 * ML_BYTES;

    int nsplit = 1;
    if (ws_size >= base_need + 4 * OP_BYTES)      nsplit = 4;
    else if (ws_size >= base_need + 2 * OP_BYTES) nsplit = 2;
    const int ntiles = (SEQ / 64) / nsplit;

    float* out = (float*)d_out;

    wprep_kernel<<<768, 256, 0, stream>>>(W[0], W[1], W[2], Whi, Wlo);

    dim3 pgrid(NB * SEQ / 16, 3);
    proj3_kernel<<<pgrid, 256, 0, stream>>>(X[0], X[1], X[2], Whi, Wlo,
                                            Bv[0], Bv[1], Bv[2], P);

    const size_t proj_elems = (size_t)NB * SEQ * DF;   // 1,048,576
    dim3 agrid(SEQ / 64, NB, nsplit);
    if (nsplit == 1) {
        attn_mfma_kernel<<<agrid, 256, 0, stream>>>(P, P + proj_elems, P + 2 * proj_elems,
                                                    out, Mp, Lp, ntiles, 1);
    } else {
        attn_mfma_kernel<<<agrid, 256, 0, stream>>>(P, P + proj_elems, P + 2 * proj_elems,
                                                    Op, Mp, Lp, ntiles, 0);
        combine_kernel<<<(NB * SEQ * 4) / 256, 256, 0, stream>>>(Op, Mp, Lp, out, nsplit);
    }
}

// Round 2
// 285.439 us; speedup vs baseline: 1.4672x; 1.2650x over previous
//
#include <hip/hip_runtime.h>

#define NB 4
#define SEQ 4096
#define DM 1024
#define DF 64

typedef unsigned short u16;
typedef unsigned int u32;
typedef __attribute__((ext_vector_type(8))) short short8;   // 8 bf16 = 4 VGPR (MFMA A/B frag)
typedef __attribute__((ext_vector_type(8))) unsigned short ushort8;
typedef __attribute__((ext_vector_type(4))) float f32x4;    // MFMA C/D frag

__device__ __forceinline__ float bf2f(u16 u) {
    union { u32 i; float f; } v; v.i = ((u32)u) << 16; return v.f;
}
__device__ __forceinline__ u16 f2bf(float f) {
    union { float f; u32 i; } v; v.f = f;
    u32 lsb = (v.i >> 16) & 1u;
    v.i += 0x7fffu + lsb;          // RNE
    return (u16)(v.i >> 16);
}

#define MFMA16(a, b, c) __builtin_amdgcn_mfma_f32_16x16x32_bf16(a, b, c, 0, 0, 0)

// ---------------- W prep: split fp32 W into bf16 hi/lo ----------------------
// 3 matrices x 64x1024. Whi[i]+Wlo[i] together carry ~16 mantissa bits.
__global__ __launch_bounds__(256) void wprep_kernel(
    const float* __restrict__ W0, const float* __restrict__ W1, const float* __restrict__ W2,
    u16* __restrict__ Whi, u16* __restrict__ Wlo)
{
    int i = blockIdx.x * 256 + threadIdx.x;            // 0 .. 3*65536-1
    const float* W = (i < 65536) ? W0 : (i < 131072) ? W1 : W2;
    float v = W[i & 65535];
    u16 hi = f2bf(v);
    Whi[i] = hi;
    Wlo[i] = f2bf(v - bf2f(hi));
}

// ---------------- Projection v4: LDS-staged split-bf16 MFMA GEMM ------------
// grid (256, 3), block 256 (4 waves). Block owns 64 rows x 64 cols, full K.
// Wave w owns rows 16w..16w+15 (complete K -> no cross-wave reduction).
// Per K-step of 64: coalesced float4 X loads -> reg -> bf16 hi/lo -> LDS;
// W tile (pre-split bf16) copied reg->LDS. Next step's globals prefetched
// into regs during the MFMA block (latency hidden under compute).
// 3-term split product: x_hi*w_hi + x_lo*w_hi + x_hi*w_lo.
// A-frag: A[m=lane&15][k=quad*8+j]; B-frag: B[k=quad*8+j][n=lane&15];
// D: col=lane&15, row=quad*4+reg  (HW-verified layout, same as attention).
#define KST 72   // padded LDS stride (u16); 16B frag reads land 2-way = free
__global__ __launch_bounds__(256) void proj4_kernel(
    const float* __restrict__ X0, const float* __restrict__ X1, const float* __restrict__ X2,
    const u16* __restrict__ Whi, const u16* __restrict__ Wlo,
    const float* __restrict__ b0, const float* __restrict__ b1, const float* __restrict__ b2,
    u16* __restrict__ Oall)
{
    __shared__ u16 xh[64 * KST];
    __shared__ u16 xl[64 * KST];
    __shared__ u16 wh_s[64 * KST];
    __shared__ u16 wl_s[64 * KST];

    const int t    = threadIdx.x;
    const int w    = t >> 6;
    const int lane = t & 63;
    const int m15  = lane & 15;
    const int quad = lane >> 4;
    const int y    = blockIdx.y;

    const float* X    = (y == 0) ? X0 : (y == 1) ? X1 : X2;
    const float* bias = (y == 0) ? b0 : (y == 1) ? b1 : b2;
    const u16*   wh   = Whi + y * 65536;
    const u16*   wl   = Wlo + y * 65536;
    u16*         O    = Oall + (size_t)y * (NB * SEQ * DF);

    const long r0 = (long)blockIdx.x * 64;

    // staging assignment
    const int xrow = t >> 4;          // X: rows xrow, +16, +32, +48; 16 lanes/row
    const int xc4  = t & 15;          //    float4 col within row (coalesced 256B/row)
    const int wrow = t >> 3;          // W: rows wrow, wrow+32; 32 lanes... (8 lanes/row)
    const int wc8  = t & 7;           //    ushort8 col within row (coalesced 128B/row)

    f32x4 acc[4];
#pragma unroll
    for (int F = 0; F < 4; ++F) acc[F] = (f32x4){0.f, 0.f, 0.f, 0.f};

    // prologue: prefetch step 0
    float4  xr[4];
    ushort8 wrh[2], wrl[2];
#pragma unroll
    for (int i = 0; i < 4; ++i)
        xr[i] = *(const float4*)(X + (r0 + xrow + 16 * i) * DM + 4 * xc4);
#pragma unroll
    for (int i = 0; i < 2; ++i) {
        wrh[i] = *(const ushort8*)(wh + (wrow + 32 * i) * DM + 8 * wc8);
        wrl[i] = *(const ushort8*)(wl + (wrow + 32 * i) * DM + 8 * wc8);
    }

    for (int s = 0; s < 16; ++s) {            // 16 K-steps of 64
        __syncthreads();   // prior step's LDS readers done
        // ---- stage X (convert fp32 -> bf16 hi/lo) ----
#pragma unroll
        for (int i = 0; i < 4; ++i) {
            const int row = xrow + 16 * i;
            float v4[4] = {xr[i].x, xr[i].y, xr[i].z, xr[i].w};
            ushort4 h, l;
            u16 hh;
            hh = f2bf(v4[0]); h.x = hh; l.x = f2bf(v4[0] - bf2f(hh));
            hh = f2bf(v4[1]); h.y = hh; l.y = f2bf(v4[1] - bf2f(hh));
            hh = f2bf(v4[2]); h.z = hh; l.z = f2bf(v4[2] - bf2f(hh));
            hh = f2bf(v4[3]); h.w = hh; l.w = f2bf(v4[3] - bf2f(hh));
            *(ushort4*)&xh[row * KST + 4 * xc4] = h;
            *(ushort4*)&xl[row * KST + 4 * xc4] = l;
        }
        // ---- stage W (already bf16, raw copy) ----
#pragma unroll
        for (int i = 0; i < 2; ++i) {
            *(ushort8*)&wh_s[(wrow + 32 * i) * KST + 8 * wc8] = wrh[i];
            *(ushort8*)&wl_s[(wrow + 32 * i) * KST + 8 * wc8] = wrl[i];
        }
        __syncthreads();   // staging visible

        // ---- prefetch step s+1 (hidden under MFMA block) ----
        if (s + 1 < 16) {
            const int k1 = 64 * (s + 1);
#pragma unroll
            for (int i = 0; i < 4; ++i)
                xr[i] = *(const float4*)(X + (r0 + xrow + 16 * i) * DM + k1 + 4 * xc4);
#pragma unroll
            for (int i = 0; i < 2; ++i) {
                wrh[i] = *(const ushort8*)(wh + (wrow + 32 * i) * DM + k1 + 8 * wc8);
                wrl[i] = *(const ushort8*)(wl + (wrow + 32 * i) * DM + k1 + 8 * wc8);
            }
        }

        // ---- MFMA block: 24 per wave ----
        const u16* ax = &xh[(16 * w + m15) * KST + quad * 8];
        const u16* alx = &xl[(16 * w + m15) * KST + quad * 8];
        short8 ah0 = *(const short8*)ax;
        short8 ah1 = *(const short8*)(ax + 32);
        short8 al0 = *(const short8*)alx;
        short8 al1 = *(const short8*)(alx + 32);
#pragma unroll
        for (int F = 0; F < 4; ++F) {
            const u16* bx  = &wh_s[(16 * F + m15) * KST + quad * 8];
            const u16* blx = &wl_s[(16 * F + m15) * KST + quad * 8];
            short8 bh0 = *(const short8*)bx;
            short8 bh1 = *(const short8*)(bx + 32);
            short8 bl0 = *(const short8*)blx;
            short8 bl1 = *(const short8*)(blx + 32);
            acc[F] = MFMA16(ah0, bh0, acc[F]);
            acc[F] = MFMA16(ah1, bh1, acc[F]);
            acc[F] = MFMA16(al0, bh0, acc[F]);
            acc[F] = MFMA16(al1, bh1, acc[F]);
            acc[F] = MFMA16(ah0, bl0, acc[F]);
            acc[F] = MFMA16(ah1, bl1, acc[F]);
        }
    }

    // ---- epilogue: bias + bf16 store ----
#pragma unroll
    for (int F = 0; F < 4; ++F) {
        float bv = bias[16 * F + m15];
#pragma unroll
        for (int r = 0; r < 4; ++r)
            O[(r0 + 16 * w + 4 * quad + r) * DF + 16 * F + m15] = f2bf(acc[F][r] + bv);
    }
}

// ---------------- MFMA flash attention (key-split) --------------------------
// grid (64, NB, nsplit), block 256 (4 waves). Block covers 64 q rows; wave w
// owns q rows q0+16w..+15; blockIdx.z covers `ntiles` 64-key tiles.
// If norm==1 (nsplit==1): normalize in-kernel, write to Opart directly.
// Else: write unnormalized O + per-row (m,l) partials for the combine kernel.
#define KSTR 72          // padded LDS stride (shorts), keeps 16B align

__global__ __launch_bounds__(256) void attn_mfma_kernel(
    const u16* __restrict__ Qg, const u16* __restrict__ Kg, const u16* __restrict__ Vg,
    float* __restrict__ Opart, float* __restrict__ Mp, float* __restrict__ Lp,
    int ntiles, int norm)
{
    __shared__ u16 ks[64 * KSTR];        // K tile, row-major [key][d]
    __shared__ u16 vt[64 * KSTR];        // V tile TRANSPOSED [f][key]
    __shared__ u16 ps[4][16 * KSTR];     // per-wave P tile [q][key]

    const int t    = threadIdx.x;
    const int w    = t >> 6;
    const int lane = t & 63;
    const int m15  = lane & 15;
    const int quad = lane >> 4;
    const int b    = blockIdx.y;
    const int z    = blockIdx.z;
    const int q0   = blockIdx.x * 64;

    // Q fragments, resident for the whole kernel (direct from global, bf16)
    const u16* qptr = Qg + ((long)(b * SEQ + q0 + 16 * w + m15)) * DF + quad * 8;
    short8 qa0 = *(const short8*)qptr;          // d 0..31 chunk
    short8 qa1 = *(const short8*)(qptr + 32);   // d 32..63 chunk

    f32x4 accO[4];
#pragma unroll
    for (int F = 0; F < 4; ++F) accO[F] = (f32x4){0.f, 0.f, 0.f, 0.f};
    float mrow[4] = {-1e30f, -1e30f, -1e30f, -1e30f};
    float lrow[4] = {0.f, 0.f, 0.f, 0.f};

    const long kvbase = ((long)b * SEQ + (long)z * ntiles * 64) * DF;
    const ushort4* kb4 = (const ushort4*)(Kg + kvbase);
    const ushort4* vb4 = (const ushort4*)(Vg + kvbase);

    // staging registers (software pipeline: global->reg ahead, reg->LDS at top)
    ushort4 kreg[4], vreg[4];
    const int krow  = t >> 4;          // K staging: rows krow, krow+16,32,48
    const int kcol4 = t & 15;
    const int vj0   = (t & 15) * 4;    // V transpose: keys vj0..vj0+3
    const int vf0   = (t >> 4) * 4;    // features vf0..vf0+3
#pragma unroll
    for (int c = 0; c < 4; ++c) {
        kreg[c] = kb4[(krow + 16 * c) * 16 + kcol4];
        vreg[c] = vb4[(vj0 + c) * 16 + (vf0 >> 2)];
    }

    for (int tile = 0; tile < ntiles; ++tile) {
        __syncthreads();   // prior tile's LDS readers done
#pragma unroll
        for (int c = 0; c < 4; ++c)    // K: raw bf16 copy
            *(ushort4*)&ks[(krow + 16 * c) * KSTR + kcol4 * 4] = kreg[c];
        {                              // V: 4x4 in-register transpose
            ushort4 w0 = {vreg[0].x, vreg[1].x, vreg[2].x, vreg[3].x};
            ushort4 w1 = {vreg[0].y, vreg[1].y, vreg[2].y, vreg[3].y};
            ushort4 w2 = {vreg[0].z, vreg[1].z, vreg[2].z, vreg[3].z};
            ushort4 w3 = {vreg[0].w, vreg[1].w, vreg[2].w, vreg[3].w};
            *(ushort4*)&vt[(vf0 + 0) * KSTR + vj0] = w0;
            *(ushort4*)&vt[(vf0 + 1) * KSTR + vj0] = w1;
            *(ushort4*)&vt[(vf0 + 2) * KSTR + vj0] = w2;
            *(ushort4*)&vt[(vf0 + 3) * KSTR + vj0] = w3;
        }
        __syncthreads();   // staging visible

        if (tile + 1 < ntiles) {       // prefetch next tile (latency hidden by compute)
#pragma unroll
            for (int c = 0; c < 4; ++c) {
                kreg[c] = kb4[(tile + 1) * 1024 + (krow + 16 * c) * 16 + kcol4];
                vreg[c] = vb4[(tile + 1) * 1024 + (vj0 + c) * 16 + (vf0 >> 2)];
            }
        }

        // ---- QK^T: 4 key-subtiles x 2 d-chunks ----
        f32x4 S[4];
#pragma unroll
        for (int T = 0; T < 4; ++T) {
            const u16* kp = &ks[(16 * T + m15) * KSTR + quad * 8];
            short8 kb0 = *(const short8*)kp;
            short8 kb1 = *(const short8*)(kp + 32);
            S[T] = MFMA16(qa0, kb0, ((f32x4){0.f, 0.f, 0.f, 0.f}));
            S[T] = MFMA16(qa1, kb1, S[T]);
        }

        // ---- online softmax (rows 4*quad+r live in this quad) ----
        float mx[4], alpha[4], mn[4], psum[4];
#pragma unroll
        for (int T = 0; T < 4; ++T)
#pragma unroll
            for (int r = 0; r < 4; ++r) S[T][r] *= 0.125f;   // 1/sqrt(64)
#pragma unroll
        for (int r = 0; r < 4; ++r) {
            mx[r] = fmaxf(fmaxf(S[0][r], S[1][r]), fmaxf(S[2][r], S[3][r]));
#pragma unroll
            for (int s = 1; s < 16; s <<= 1) mx[r] = fmaxf(mx[r], __shfl_xor(mx[r], s));
            mn[r] = fmaxf(mrow[r], mx[r]);
            alpha[r] = __expf(mrow[r] - mn[r]);
            mrow[r] = mn[r];
            psum[r] = 0.f;
        }
#pragma unroll
        for (int T = 0; T < 4; ++T)
#pragma unroll
            for (int r = 0; r < 4; ++r) {
                float p = __expf(S[T][r] - mn[r]);
                psum[r] += p;
                ps[w][(4 * quad + r) * KSTR + 16 * T + m15] = f2bf(p);
            }
#pragma unroll
        for (int r = 0; r < 4; ++r) {
#pragma unroll
            for (int s = 1; s < 16; s <<= 1) psum[r] += __shfl_xor(psum[r], s);
            lrow[r] = lrow[r] * alpha[r] + psum[r];
        }
#pragma unroll
        for (int F = 0; F < 4; ++F)
#pragma unroll
            for (int r = 0; r < 4; ++r) accO[F][r] *= alpha[r];

        // ---- PV: A = P (same-wave region, no barrier needed), B = Vt ----
        const u16* pp = &ps[w][m15 * KSTR + quad * 8];
        short8 pa0 = *(const short8*)pp;          // keys 0..31
        short8 pa1 = *(const short8*)(pp + 32);   // keys 32..63
#pragma unroll
        for (int F = 0; F < 4; ++F) {
            const u16* vp = &vt[(16 * F + m15) * KSTR + quad * 8];
            short8 vb0 = *(const short8*)vp;
            short8 vb1 = *(const short8*)(vp + 32);
            accO[F] = MFMA16(pa0, vb0, accO[F]);
            accO[F] = MFMA16(pa1, vb1, accO[F]);
        }
    }

    // ---- epilogue ----
    const long rowbase = (long)b * SEQ + q0 + 16 * w;
    if (norm) {
        float il[4];
#pragma unroll
        for (int r = 0; r < 4; ++r) il[r] = 1.f / lrow[r];
#pragma unroll
        for (int F = 0; F < 4; ++F)
#pragma unroll
            for (int r = 0; r < 4; ++r)
                Opart[(rowbase + 4 * quad + r) * DF + 16 * F + m15] = accO[F][r] * il[r];
    } else {
        float* Og = Opart + (size_t)z * (NB * SEQ * DF);
#pragma unroll
        for (int F = 0; F < 4; ++F)
#pragma unroll
            for (int r = 0; r < 4; ++r)
                Og[(rowbase + 4 * quad + r) * DF + 16 * F + m15] = accO[F][r];
        if (m15 == 0) {
#pragma unroll
            for (int r = 0; r < 4; ++r) {
                long rg = (long)z * (NB * SEQ) + rowbase + 4 * quad + r;
                Mp[rg] = mrow[r];
                Lp[rg] = lrow[r];
            }
        }
    }
}

// ---------------- combine: merge key-split flash partials -------------------
// out[row][f] = sum_g O_g[row][f] * e^{m_g - M} / (sum_g l_g * e^{m_g - M})
// 65536 threads: 4 threads/row, 16 features each.
__global__ __launch_bounds__(256) void combine_kernel(
    const float* __restrict__ Opart, const float* __restrict__ Mp, const float* __restrict__ Lp,
    float* __restrict__ out, int nsplit)
{
    const int tg  = blockIdx.x * 256 + threadIdx.x;
    const int row = tg >> 2;
    const int f0  = (tg & 3) * 16;

    float m = -1e30f;
    for (int g = 0; g < nsplit; ++g) m = fmaxf(m, Mp[g * (NB * SEQ) + row]);

    float l = 0.f;
    float4 o[4];
#pragma unroll
    for (int i = 0; i < 4; ++i) o[i] = (float4){0.f, 0.f, 0.f, 0.f};

    for (int g = 0; g < nsplit; ++g) {
        float e = __expf(Mp[g * (NB * SEQ) + row] - m);
        l += Lp[g * (NB * SEQ) + row] * e;
        const float* Op = Opart + ((long)g * (NB * SEQ) + row) * DF + f0;
#pragma unroll
        for (int i = 0; i < 4; ++i) {
            float4 v = *(const float4*)(Op + 4 * i);
            o[i].x += v.x * e; o[i].y += v.y * e; o[i].z += v.z * e; o[i].w += v.w * e;
        }
    }
    const float inv = 1.f / l;
#pragma unroll
    for (int i = 0; i < 4; ++i) {
        float4 v = {o[i].x * inv, o[i].y * inv, o[i].z * inv, o[i].w * inv};
        *(float4*)(out + (long)row * DF + f0 + 4 * i) = v;
    }
}

extern "C" void kernel_launch(void* const* d_in, const int* in_sizes, int n_in,
                              void* d_out, int out_size, void* d_ws, size_t ws_size,
                              hipStream_t stream) {
    (void)in_sizes; (void)n_in; (void)out_size;

    const float* X[3]  = { (const float*)d_in[0], (const float*)d_in[1], (const float*)d_in[2] };
    const float* W[3]  = { (const float*)d_in[3], (const float*)d_in[5], (const float*)d_in[7] };
    const float* Bv[3] = { (const float*)d_in[4], (const float*)d_in[6], (const float*)d_in[8] };

    char* wsb = (char*)d_ws;
    // workspace layout (bytes):
    const size_t P_BYTES  = (size_t)3 * NB * SEQ * DF * 2;   // 6,291,456  (Q,K,V bf16)
    const size_t WH_BYTES = (size_t)3 * DF * DM * 2;         //   393,216  (Whi / Wlo each)
    const size_t ML_BYTES = (size_t)4 * NB * SEQ * 4;        //   262,144  (Mp / Lp each, max 4 splits)
    const size_t OP_BYTES = (size_t)NB * SEQ * DF * 4;       // 4,194,304  (per split)

    u16*   P   = (u16*)wsb;
    u16*   Whi = (u16*)(wsb + P_BYTES);
    u16*   Wlo = (u16*)(wsb + P_BYTES + WH_BYTES);
    float* Mp  = (float*)(wsb + P_BYTES + 2 * WH_BYTES);
    float* Lp  = (float*)(wsb + P_BYTES + 2 * WH_BYTES + ML_BYTES);
    float* Op  = (float*)(wsb + P_BYTES + 2 * WH_BYTES + 2 * ML_BYTES);
    const size_t base_need = P_BYTES + 2 * WH_BYTES + 2 * ML_BYTES;

    int nsplit = 1;
    if (ws_size >= base_need + 4 * OP_BYTES)      nsplit = 4;
    else if (ws_size >= base_need + 2 * OP_BYTES) nsplit = 2;
    const int ntiles = (SEQ / 64) / nsplit;

    float* out = (float*)d_out;

    wprep_kernel<<<768, 256, 0, stream>>>(W[0], W[1], W[2], Whi, Wlo);

    dim3 pgrid(NB * SEQ / 64, 3);
    proj4_kernel<<<pgrid, 256, 0, stream>>>(X[0], X[1], X[2], Whi, Wlo,
                                            Bv[0], Bv[1], Bv[2], P);

    const size_t proj_elems = (size_t)NB * SEQ * DF;   // 1,048,576
    dim3 agrid(SEQ / 64, NB, nsplit);
    if (nsplit == 1) {
        attn_mfma_kernel<<<agrid, 256, 0, stream>>>(P, P + proj_elems, P + 2 * proj_elems,
                                                    out, Mp, Lp, ntiles, 1);
    } else {
        attn_mfma_kernel<<<agrid, 256, 0, stream>>>(P, P + proj_elems, P + 2 * proj_elems,
                                                    Op, Mp, Lp, ntiles, 0);
        combine_kernel<<<(NB * SEQ * 4) / 256, 256, 0, stream>>>(Op, Mp, Lp, out, nsplit);
    }
}

// Round 3
// 281.718 us; speedup vs baseline: 1.4866x; 1.0132x over previous
//
#include <hip/hip_runtime.h>

#define NB 4
#define SEQ 4096
#define DM 1024
#define DF 64

typedef unsigned short u16;
typedef unsigned int u32;
typedef __attribute__((ext_vector_type(8))) _Float16 half8;        // 8 f16 = 4 VGPR (MFMA A/B frag)
typedef __attribute__((ext_vector_type(8))) unsigned short ushort8;
typedef __attribute__((ext_vector_type(4))) float f32x4;           // MFMA C/D frag

__device__ __forceinline__ u16 f2h(float f) {
    union { _Float16 h; u16 u; } v; v.h = (_Float16)f; return v.u;
}

#define MFMAH(a, b, c) __builtin_amdgcn_mfma_f32_16x16x32_f16(a, b, c, 0, 0, 0)

// ---------------- W prep: convert fp32 W to f16 -----------------------------
// 3 matrices x 64x1024. f16 (10 mantissa bits) GEMM error < old bf16 storage
// error, so no hi/lo split needed (see round-3 analysis).
__global__ __launch_bounds__(256) void wprep_kernel(
    const float* __restrict__ W0, const float* __restrict__ W1, const float* __restrict__ W2,
    u16* __restrict__ Wh)
{
    int i = blockIdx.x * 256 + threadIdx.x;            // 0 .. 3*65536-1
    const float* W = (i < 65536) ? W0 : (i < 131072) ? W1 : W2;
    Wh[i] = f2h(W[i & 65535]);
}

// ---------------- Projection v5: LDS-staged f16 MFMA GEMM -------------------
// grid (256, 3), block 256 (4 waves). Block owns 64 rows x 64 cols, full K.
// Wave w owns rows 16w..16w+15 (complete K -> no cross-wave reduction).
// Per K-step of 64: coalesced float4 X loads -> reg -> f16 -> LDS; W tile
// (pre-converted f16) copied reg->LDS. Next step's globals prefetched into
// regs during the MFMA block. Single-term f16 product (no split).
// A-frag: A[m=lane&15][k=quad*8+j]; B-frag: B[k=quad*8+j][n=lane&15];
// D: col=lane&15, row=quad*4+reg  (HW-verified layout, same as attention).
#define KST 72   // padded LDS stride (u16)
__global__ __launch_bounds__(256) void proj5_kernel(
    const float* __restrict__ X0, const float* __restrict__ X1, const float* __restrict__ X2,
    const u16* __restrict__ Wh,
    const float* __restrict__ b0, const float* __restrict__ b1, const float* __restrict__ b2,
    u16* __restrict__ Oall)
{
    __shared__ u16 xs[64 * KST];
    __shared__ u16 ws[64 * KST];

    const int t    = threadIdx.x;
    const int w    = t >> 6;
    const int lane = t & 63;
    const int m15  = lane & 15;
    const int quad = lane >> 4;
    const int y    = blockIdx.y;

    const float* X    = (y == 0) ? X0 : (y == 1) ? X1 : X2;
    const float* bias = (y == 0) ? b0 : (y == 1) ? b1 : b2;
    const u16*   wp   = Wh + y * 65536;
    u16*         O    = Oall + (size_t)y * (NB * SEQ * DF);

    const long r0 = (long)blockIdx.x * 64;

    // staging assignment
    const int xrow = t >> 4;          // X: rows xrow, +16, +32, +48; 16 lanes/row
    const int xc4  = t & 15;          //    float4 col within row (coalesced 256B/row)
    const int wrow = t >> 3;          // W: rows wrow, wrow+32; 8 lanes/row
    const int wc8  = t & 7;           //    ushort8 col within row (coalesced 128B/row)

    f32x4 acc[4];
#pragma unroll
    for (int F = 0; F < 4; ++F) acc[F] = (f32x4){0.f, 0.f, 0.f, 0.f};

    // prologue: prefetch step 0
    float4  xr[4];
    ushort8 wr[2];
#pragma unroll
    for (int i = 0; i < 4; ++i)
        xr[i] = *(const float4*)(X + (r0 + xrow + 16 * i) * DM + 4 * xc4);
#pragma unroll
    for (int i = 0; i < 2; ++i)
        wr[i] = *(const ushort8*)(wp + (wrow + 32 * i) * DM + 8 * wc8);

    for (int s = 0; s < 16; ++s) {            // 16 K-steps of 64
        __syncthreads();   // prior step's LDS readers done
        // ---- stage X (convert fp32 -> f16) ----
#pragma unroll
        for (int i = 0; i < 4; ++i) {
            const int row = xrow + 16 * i;
            ushort4 h;
            h.x = f2h(xr[i].x); h.y = f2h(xr[i].y);
            h.z = f2h(xr[i].z); h.w = f2h(xr[i].w);
            *(ushort4*)&xs[row * KST + 4 * xc4] = h;
        }
        // ---- stage W (already f16, raw copy) ----
#pragma unroll
        for (int i = 0; i < 2; ++i)
            *(ushort8*)&ws[(wrow + 32 * i) * KST + 8 * wc8] = wr[i];
        __syncthreads();   // staging visible

        // ---- prefetch step s+1 (hidden under MFMA block) ----
        if (s + 1 < 16) {
            const int k1 = 64 * (s + 1);
#pragma unroll
            for (int i = 0; i < 4; ++i)
                xr[i] = *(const float4*)(X + (r0 + xrow + 16 * i) * DM + k1 + 4 * xc4);
#pragma unroll
            for (int i = 0; i < 2; ++i)
                wr[i] = *(const ushort8*)(wp + (wrow + 32 * i) * DM + k1 + 8 * wc8);
        }

        // ---- MFMA block: 8 per wave ----
        const u16* ax = &xs[(16 * w + m15) * KST + quad * 8];
        half8 a0 = *(const half8*)ax;
        half8 a1 = *(const half8*)(ax + 32);
#pragma unroll
        for (int F = 0; F < 4; ++F) {
            const u16* bx = &ws[(16 * F + m15) * KST + quad * 8];
            half8 b0 = *(const half8*)bx;
            half8 b1 = *(const half8*)(bx + 32);
            acc[F] = MFMAH(a0, b0, acc[F]);
            acc[F] = MFMAH(a1, b1, acc[F]);
        }
    }

    // ---- epilogue: bias + f16 store ----
#pragma unroll
    for (int F = 0; F < 4; ++F) {
        float bv = bias[16 * F + m15];
#pragma unroll
        for (int r = 0; r < 4; ++r)
            O[(r0 + 16 * w + 4 * quad + r) * DF + 16 * F + m15] = f2h(acc[F][r] + bv);
    }
}

// ---------------- MFMA flash attention (key-split, f16) ---------------------
// grid (64, NB, nsplit), block 256 (4 waves). Block covers 64 q rows; wave w
// owns q rows q0+16w..+15; blockIdx.z covers `ntiles` 64-key tiles.
// If norm==1 (nsplit==1): normalize in-kernel, write to Opart directly.
// Else: write unnormalized O + per-row (m,l) partials for the combine kernel.
#define KSTR 72          // padded LDS stride (shorts), keeps 16B align

__global__ __launch_bounds__(256) void attn_mfma_kernel(
    const u16* __restrict__ Qg, const u16* __restrict__ Kg, const u16* __restrict__ Vg,
    float* __restrict__ Opart, float* __restrict__ Mp, float* __restrict__ Lp,
    int ntiles, int norm)
{
    __shared__ u16 ks[64 * KSTR];        // K tile, row-major [key][d]
    __shared__ u16 vt[64 * KSTR];        // V tile TRANSPOSED [f][key]
    __shared__ u16 ps[4][16 * KSTR];     // per-wave P tile [q][key]

    const int t    = threadIdx.x;
    const int w    = t >> 6;
    const int lane = t & 63;
    const int m15  = lane & 15;
    const int quad = lane >> 4;
    const int b    = blockIdx.y;
    const int z    = blockIdx.z;
    const int q0   = blockIdx.x * 64;

    // Q fragments, resident for the whole kernel (direct from global, f16)
    const u16* qptr = Qg + ((long)(b * SEQ + q0 + 16 * w + m15)) * DF + quad * 8;
    half8 qa0 = *(const half8*)qptr;          // d 0..31 chunk
    half8 qa1 = *(const half8*)(qptr + 32);   // d 32..63 chunk

    f32x4 accO[4];
#pragma unroll
    for (int F = 0; F < 4; ++F) accO[F] = (f32x4){0.f, 0.f, 0.f, 0.f};
    float mrow[4] = {-1e30f, -1e30f, -1e30f, -1e30f};
    float lrow[4] = {0.f, 0.f, 0.f, 0.f};

    const long kvbase = ((long)b * SEQ + (long)z * ntiles * 64) * DF;
    const ushort4* kb4 = (const ushort4*)(Kg + kvbase);
    const ushort4* vb4 = (const ushort4*)(Vg + kvbase);

    // staging registers (software pipeline: global->reg ahead, reg->LDS at top)
    ushort4 kreg[4], vreg[4];
    const int krow  = t >> 4;          // K staging: rows krow, krow+16,32,48
    const int kcol4 = t & 15;
    const int vj0   = (t & 15) * 4;    // V transpose: keys vj0..vj0+3
    const int vf0   = (t >> 4) * 4;    // features vf0..vf0+3
#pragma unroll
    for (int c = 0; c < 4; ++c) {
        kreg[c] = kb4[(krow + 16 * c) * 16 + kcol4];
        vreg[c] = vb4[(vj0 + c) * 16 + (vf0 >> 2)];
    }

    for (int tile = 0; tile < ntiles; ++tile) {
        __syncthreads();   // prior tile's LDS readers done
#pragma unroll
        for (int c = 0; c < 4; ++c)    // K: raw f16 copy
            *(ushort4*)&ks[(krow + 16 * c) * KSTR + kcol4 * 4] = kreg[c];
        {                              // V: 4x4 in-register transpose
            ushort4 w0 = {vreg[0].x, vreg[1].x, vreg[2].x, vreg[3].x};
            ushort4 w1 = {vreg[0].y, vreg[1].y, vreg[2].y, vreg[3].y};
            ushort4 w2 = {vreg[0].z, vreg[1].z, vreg[2].z, vreg[3].z};
            ushort4 w3 = {vreg[0].w, vreg[1].w, vreg[2].w, vreg[3].w};
            *(ushort4*)&vt[(vf0 + 0) * KSTR + vj0] = w0;
            *(ushort4*)&vt[(vf0 + 1) * KSTR + vj0] = w1;
            *(ushort4*)&vt[(vf0 + 2) * KSTR + vj0] = w2;
            *(ushort4*)&vt[(vf0 + 3) * KSTR + vj0] = w3;
        }
        __syncthreads();   // staging visible

        if (tile + 1 < ntiles) {       // prefetch next tile (latency hidden by compute)
#pragma unroll
            for (int c = 0; c < 4; ++c) {
                kreg[c] = kb4[(tile + 1) * 1024 + (krow + 16 * c) * 16 + kcol4];
                vreg[c] = vb4[(tile + 1) * 1024 + (vj0 + c) * 16 + (vf0 >> 2)];
            }
        }

        // ---- QK^T: 4 key-subtiles x 2 d-chunks ----
        f32x4 S[4];
#pragma unroll
        for (int T = 0; T < 4; ++T) {
            const u16* kp = &ks[(16 * T + m15) * KSTR + quad * 8];
            half8 kb0 = *(const half8*)kp;
            half8 kb1 = *(const half8*)(kp + 32);
            S[T] = MFMAH(qa0, kb0, ((f32x4){0.f, 0.f, 0.f, 0.f}));
            S[T] = MFMAH(qa1, kb1, S[T]);
        }

        // ---- online softmax (rows 4*quad+r live in this quad) ----
        float mx[4], alpha[4], mn[4], psum[4];
#pragma unroll
        for (int T = 0; T < 4; ++T)
#pragma unroll
            for (int r = 0; r < 4; ++r) S[T][r] *= 0.125f;   // 1/sqrt(64)
#pragma unroll
        for (int r = 0; r < 4; ++r) {
            mx[r] = fmaxf(fmaxf(S[0][r], S[1][r]), fmaxf(S[2][r], S[3][r]));
#pragma unroll
            for (int s = 1; s < 16; s <<= 1) mx[r] = fmaxf(mx[r], __shfl_xor(mx[r], s));
            mn[r] = fmaxf(mrow[r], mx[r]);
            alpha[r] = __expf(mrow[r] - mn[r]);
            mrow[r] = mn[r];
            psum[r] = 0.f;
        }
#pragma unroll
        for (int T = 0; T < 4; ++T)
#pragma unroll
            for (int r = 0; r < 4; ++r) {
                float p = __expf(S[T][r] - mn[r]);
                psum[r] += p;
                ps[w][(4 * quad + r) * KSTR + 16 * T + m15] = f2h(p);
            }
#pragma unroll
        for (int r = 0; r < 4; ++r) {
#pragma unroll
            for (int s = 1; s < 16; s <<= 1) psum[r] += __shfl_xor(psum[r], s);
            lrow[r] = lrow[r] * alpha[r] + psum[r];
        }
#pragma unroll
        for (int F = 0; F < 4; ++F)
#pragma unroll
            for (int r = 0; r < 4; ++r) accO[F][r] *= alpha[r];

        // ---- PV: A = P (same-wave region, no barrier needed), B = Vt ----
        const u16* pp = &ps[w][m15 * KSTR + quad * 8];
        half8 pa0 = *(const half8*)pp;          // keys 0..31
        half8 pa1 = *(const half8*)(pp + 32);   // keys 32..63
#pragma unroll
        for (int F = 0; F < 4; ++F) {
            const u16* vp = &vt[(16 * F + m15) * KSTR + quad * 8];
            half8 vb0 = *(const half8*)vp;
            half8 vb1 = *(const half8*)(vp + 32);
            accO[F] = MFMAH(pa0, vb0, accO[F]);
            accO[F] = MFMAH(pa1, vb1, accO[F]);
        }
    }

    // ---- epilogue ----
    const long rowbase = (long)b * SEQ + q0 + 16 * w;
    if (norm) {
        float il[4];
#pragma unroll
        for (int r = 0; r < 4; ++r) il[r] = 1.f / lrow[r];
#pragma unroll
        for (int F = 0; F < 4; ++F)
#pragma unroll
            for (int r = 0; r < 4; ++r)
                Opart[(rowbase + 4 * quad + r) * DF + 16 * F + m15] = accO[F][r] * il[r];
    } else {
        float* Og = Opart + (size_t)z * (NB * SEQ * DF);
#pragma unroll
        for (int F = 0; F < 4; ++F)
#pragma unroll
            for (int r = 0; r < 4; ++r)
                Og[(rowbase + 4 * quad + r) * DF + 16 * F + m15] = accO[F][r];
        if (m15 == 0) {
#pragma unroll
            for (int r = 0; r < 4; ++r) {
                long rg = (long)z * (NB * SEQ) + rowbase + 4 * quad + r;
                Mp[rg] = mrow[r];
                Lp[rg] = lrow[r];
            }
        }
    }
}

// ---------------- combine: merge key-split flash partials -------------------
// out[row][f] = sum_g O_g[row][f] * e^{m_g - M} / (sum_g l_g * e^{m_g - M})
// 65536 threads: 4 threads/row, 16 features each.
__global__ __launch_bounds__(256) void combine_kernel(
    const float* __restrict__ Opart, const float* __restrict__ Mp, const float* __restrict__ Lp,
    float* __restrict__ out, int nsplit)
{
    const int tg  = blockIdx.x * 256 + threadIdx.x;
    const int row = tg >> 2;
    const int f0  = (tg & 3) * 16;

    float m = -1e30f;
    for (int g = 0; g < nsplit; ++g) m = fmaxf(m, Mp[g * (NB * SEQ) + row]);

    float l = 0.f;
    float4 o[4];
#pragma unroll
    for (int i = 0; i < 4; ++i) o[i] = (float4){0.f, 0.f, 0.f, 0.f};

    for (int g = 0; g < nsplit; ++g) {
        float e = __expf(Mp[g * (NB * SEQ) + row] - m);
        l += Lp[g * (NB * SEQ) + row] * e;
        const float* Op = Opart + ((long)g * (NB * SEQ) + row) * DF + f0;
#pragma unroll
        for (int i = 0; i < 4; ++i) {
            float4 v = *(const float4*)(Op + 4 * i);
            o[i].x += v.x * e; o[i].y += v.y * e; o[i].z += v.z * e; o[i].w += v.w * e;
        }
    }
    const float inv = 1.f / l;
#pragma unroll
    for (int i = 0; i < 4; ++i) {
        float4 v = {o[i].x * inv, o[i].y * inv, o[i].z * inv, o[i].w * inv};
        *(float4*)(out + (long)row * DF + f0 + 4 * i) = v;
    }
}

extern "C" void kernel_launch(void* const* d_in, const int* in_sizes, int n_in,
                              void* d_out, int out_size, void* d_ws, size_t ws_size,
                              hipStream_t stream) {
    (void)in_sizes; (void)n_in; (void)out_size;

    const float* X[3]  = { (const float*)d_in[0], (const float*)d_in[1], (const float*)d_in[2] };
    const float* W[3]  = { (const float*)d_in[3], (const float*)d_in[5], (const float*)d_in[7] };
    const float* Bv[3] = { (const float*)d_in[4], (const float*)d_in[6], (const float*)d_in[8] };

    char* wsb = (char*)d_ws;
    // workspace layout (bytes):
    const size_t P_BYTES  = (size_t)3 * NB * SEQ * DF * 2;   // 6,291,456  (Q,K,V f16)
    const size_t WH_BYTES = (size_t)3 * DF * DM * 2;         //   393,216  (Wh f16)
    const size_t ML_BYTES = (size_t)4 * NB * SEQ * 4;        //   262,144  (Mp / Lp each, max 4 splits)
    const size_t OP_BYTES = (size_t)NB * SEQ * DF * 4;       // 4,194,304  (per split)

    u16*   P   = (u16*)wsb;
    u16*   Wh  = (u16*)(wsb + P_BYTES);
    float* Mp  = (float*)(wsb + P_BYTES + WH_BYTES);
    float* Lp  = (float*)(wsb + P_BYTES + WH_BYTES + ML_BYTES);
    float* Op  = (float*)(wsb + P_BYTES + WH_BYTES + 2 * ML_BYTES);
    const size_t base_need = P_BYTES + WH_BYTES + 2 * ML_BYTES;

    int nsplit = 1;
    if (ws_size >= base_need + 4 * OP_BYTES)      nsplit = 4;
    else if (ws_size >= base_need + 2 * OP_BYTES) nsplit = 2;
    const int ntiles = (SEQ / 64) / nsplit;

    float* out = (float*)d_out;

    wprep_kernel<<<768, 256, 0, stream>>>(W[0], W[1], W[2], Wh);

    dim3 pgrid(NB * SEQ / 64, 3);
    proj5_kernel<<<pgrid, 256, 0, stream>>>(X[0], X[1], X[2], Wh,
                                            Bv[0], Bv[1], Bv[2], P);

    const size_t proj_elems = (size_t)NB * SEQ * DF;   // 1,048,576
    dim3 agrid(SEQ / 64, NB, nsplit);
    if (nsplit == 1) {
        attn_mfma_kernel<<<agrid, 256, 0, stream>>>(P, P + proj_elems, P + 2 * proj_elems,
                                                    out, Mp, Lp, ntiles, 1);
    } else {
        attn_mfma_kernel<<<agrid, 256, 0, stream>>>(P, P + proj_elems, P + 2 * proj_elems,
                                                    Op, Mp, Lp, ntiles, 0);
        combine_kernel<<<(NB * SEQ * 4) / 256, 256, 0, stream>>>(Op, Mp, Lp, out, nsplit);
    }
}

// Round 4
// 280.874 us; speedup vs baseline: 1.4910x; 1.0030x over previous
//
#include <hip/hip_runtime.h>

#define NB 4
#define SEQ 4096
#define DM 1024
#define DF 64

typedef unsigned short u16;
typedef unsigned int u32;
typedef __attribute__((ext_vector_type(8))) _Float16 half8;        // 8 f16 = 4 VGPR (MFMA A/B frag)
typedef __attribute__((ext_vector_type(8))) unsigned short ushort8;
typedef __attribute__((ext_vector_type(4))) float f32x4;           // MFMA C/D frag

__device__ __forceinline__ u16 f2h(float f) {
    union { _Float16 h; u16 u; } v; v.h = (_Float16)f; return v.u;
}

#define MFMAH(a, b, c) __builtin_amdgcn_mfma_f32_16x16x32_f16(a, b, c, 0, 0, 0)

// ---------------- W prep: convert fp32 W to f16 -----------------------------
__global__ __launch_bounds__(256) void wprep_kernel(
    const float* __restrict__ W0, const float* __restrict__ W1, const float* __restrict__ W2,
    u16* __restrict__ Wh)
{
    int i = blockIdx.x * 256 + threadIdx.x;            // 0 .. 3*65536-1
    const float* W = (i < 65536) ? W0 : (i < 131072) ? W1 : W2;
    Wh[i] = f2h(W[i & 65535]);
}

// ---------------- Projection v6: double-buffered 8-wave f16 MFMA GEMM -------
// grid (256, 3), block 512 (8 waves). Block owns 64 rows x 64 cols, full K.
// Wave w: wr=w&3 owns rows 16*wr.., wf=w>>2 owns cols 32*wf.. (2 F-tiles).
// 24 waves/CU (3 blocks x 8) vs v5's 12 -> 2x latency-hiding TLP.
// LDS double-buffered: step s computes from buf[s&1] while staging s+1 into
// buf[s^1] and prefetching s+2 from global -> ONE barrier per K-step (v5: 2).
// A-frag: A[m=lane&15][k=quad*8+j]; B-frag: B[k=quad*8+j][n=lane&15];
// D: col=lane&15, row=quad*4+reg  (HW-verified layout, same as attention).
#define KST 72   // padded LDS stride (u16): frag reads land 2-way = free
__global__ __launch_bounds__(512, 6) void proj6_kernel(
    const float* __restrict__ X0, const float* __restrict__ X1, const float* __restrict__ X2,
    const u16* __restrict__ Wh,
    const float* __restrict__ b0, const float* __restrict__ b1, const float* __restrict__ b2,
    u16* __restrict__ Oall)
{
    __shared__ u16 xs[2][64 * KST];
    __shared__ u16 wt[2][64 * KST];

    const int t    = threadIdx.x;
    const int w    = t >> 6;
    const int lane = t & 63;
    const int m15  = lane & 15;
    const int quad = lane >> 4;
    const int wr   = w & 3;          // row group: rows 16*wr..16*wr+15
    const int wf   = w >> 2;         // col group: F-tiles 2*wf, 2*wf+1
    const int y    = blockIdx.y;

    const float* X    = (y == 0) ? X0 : (y == 1) ? X1 : X2;
    const float* bias = (y == 0) ? b0 : (y == 1) ? b1 : b2;
    const u16*   wp   = Wh + y * 65536;
    u16*         O    = Oall + (size_t)y * (NB * SEQ * DF);

    const long r0 = (long)blockIdx.x * 64;

    // staging assignment (512 threads)
    const int xrow = t >> 3;          // X/W row 0..63; 8 lanes per row
    const int c8   = t & 7;           // X: float4 cols c8, c8+8; W: ushort8 col c8

    f32x4 acc[2];
    acc[0] = (f32x4){0.f, 0.f, 0.f, 0.f};
    acc[1] = (f32x4){0.f, 0.f, 0.f, 0.f};

    const float* xbase = X + (r0 + xrow) * DM;
    const u16*   wbase = wp + xrow * DM;

    float4  xr2[2];
    ushort8 wreg;

    // prologue: stage step 0 into buf0, prefetch step 1
    xr2[0] = *(const float4*)(xbase + 4 * c8);
    xr2[1] = *(const float4*)(xbase + 4 * c8 + 32);
    wreg   = *(const ushort8*)(wbase + 8 * c8);
    {
        ushort4 h0, h1;
        h0.x = f2h(xr2[0].x); h0.y = f2h(xr2[0].y); h0.z = f2h(xr2[0].z); h0.w = f2h(xr2[0].w);
        h1.x = f2h(xr2[1].x); h1.y = f2h(xr2[1].y); h1.z = f2h(xr2[1].z); h1.w = f2h(xr2[1].w);
        *(ushort4*)&xs[0][xrow * KST + 4 * c8]      = h0;
        *(ushort4*)&xs[0][xrow * KST + 4 * c8 + 32] = h1;
        *(ushort8*)&wt[0][xrow * KST + 8 * c8]      = wreg;
    }
    xr2[0] = *(const float4*)(xbase + 64 + 4 * c8);
    xr2[1] = *(const float4*)(xbase + 64 + 4 * c8 + 32);
    wreg   = *(const ushort8*)(wbase + 64 + 8 * c8);
    __syncthreads();   // buf0 visible

    for (int s = 0; s < 16; ++s) {            // 16 K-steps of 64, 1 barrier each
        const int cur = s & 1, nxt = cur ^ 1;

        // ---- stage step s+1 into buf[nxt] (regs loaded 1 step ago) ----
        if (s + 1 < 16) {
            ushort4 h0, h1;
            h0.x = f2h(xr2[0].x); h0.y = f2h(xr2[0].y); h0.z = f2h(xr2[0].z); h0.w = f2h(xr2[0].w);
            h1.x = f2h(xr2[1].x); h1.y = f2h(xr2[1].y); h1.z = f2h(xr2[1].z); h1.w = f2h(xr2[1].w);
            *(ushort4*)&xs[nxt][xrow * KST + 4 * c8]      = h0;
            *(ushort4*)&xs[nxt][xrow * KST + 4 * c8 + 32] = h1;
            *(ushort8*)&wt[nxt][xrow * KST + 8 * c8]      = wreg;
        }
        // ---- prefetch step s+2 from global (hidden under MFMA) ----
        if (s + 2 < 16) {
            const int k2 = 64 * (s + 2);
            xr2[0] = *(const float4*)(xbase + k2 + 4 * c8);
            xr2[1] = *(const float4*)(xbase + k2 + 4 * c8 + 32);
            wreg   = *(const ushort8*)(wbase + k2 + 8 * c8);
        }

        // ---- MFMA phase: 4 per wave from buf[cur] ----
        const u16* ax = &xs[cur][(16 * wr + m15) * KST + quad * 8];
        half8 a0 = *(const half8*)ax;
        half8 a1 = *(const half8*)(ax + 32);
#pragma unroll
        for (int Fi = 0; Fi < 2; ++Fi) {
            const u16* bx = &wt[cur][(16 * (2 * wf + Fi) + m15) * KST + quad * 8];
            half8 bb0 = *(const half8*)bx;
            half8 bb1 = *(const half8*)(bx + 32);
            acc[Fi] = MFMAH(a0, bb0, acc[Fi]);
            acc[Fi] = MFMAH(a1, bb1, acc[Fi]);
        }
        __syncthreads();   // buf[nxt] visible for s+1; buf[cur] free for s+1's stage
    }

    // ---- epilogue: bias + f16 store (wave writes 16 rows x 32 cols) ----
#pragma unroll
    for (int Fi = 0; Fi < 2; ++Fi) {
        const int fcol = 16 * (2 * wf + Fi) + m15;
        float bv = bias[fcol];
#pragma unroll
        for (int r = 0; r < 4; ++r)
            O[(r0 + 16 * wr + 4 * quad + r) * DF + fcol] = f2h(acc[Fi][r] + bv);
    }
}

// ---------------- MFMA flash attention (key-split, f16) ---------------------
// grid (64, NB, nsplit), block 256 (4 waves). Block covers 64 q rows; wave w
// owns q rows q0+16w..+15; blockIdx.z covers `ntiles` 64-key tiles.
// If norm==1 (nsplit==1): normalize in-kernel, write to Opart directly.
// Else: write unnormalized O + per-row (m,l) partials for the combine kernel.
#define KSTR 72          // padded LDS stride (shorts), keeps 16B align

__global__ __launch_bounds__(256) void attn_mfma_kernel(
    const u16* __restrict__ Qg, const u16* __restrict__ Kg, const u16* __restrict__ Vg,
    float* __restrict__ Opart, float* __restrict__ Mp, float* __restrict__ Lp,
    int ntiles, int norm)
{
    __shared__ u16 ks[64 * KSTR];        // K tile, row-major [key][d]
    __shared__ u16 vt[64 * KSTR];        // V tile TRANSPOSED [f][key]
    __shared__ u16 ps[4][16 * KSTR];     // per-wave P tile [q][key]

    const int t    = threadIdx.x;
    const int w    = t >> 6;
    const int lane = t & 63;
    const int m15  = lane & 15;
    const int quad = lane >> 4;
    const int b    = blockIdx.y;
    const int z    = blockIdx.z;
    const int q0   = blockIdx.x * 64;

    // Q fragments, resident for the whole kernel (direct from global, f16)
    const u16* qptr = Qg + ((long)(b * SEQ + q0 + 16 * w + m15)) * DF + quad * 8;
    half8 qa0 = *(const half8*)qptr;          // d 0..31 chunk
    half8 qa1 = *(const half8*)(qptr + 32);   // d 32..63 chunk

    f32x4 accO[4];
#pragma unroll
    for (int F = 0; F < 4; ++F) accO[F] = (f32x4){0.f, 0.f, 0.f, 0.f};
    float mrow[4] = {-1e30f, -1e30f, -1e30f, -1e30f};
    float lrow[4] = {0.f, 0.f, 0.f, 0.f};

    const long kvbase = ((long)b * SEQ + (long)z * ntiles * 64) * DF;
    const ushort4* kb4 = (const ushort4*)(Kg + kvbase);
    const ushort4* vb4 = (const ushort4*)(Vg + kvbase);

    // staging registers (software pipeline: global->reg ahead, reg->LDS at top)
    ushort4 kreg[4], vreg[4];
    const int krow  = t >> 4;          // K staging: rows krow, krow+16,32,48
    const int kcol4 = t & 15;
    const int vj0   = (t & 15) * 4;    // V transpose: keys vj0..vj0+3
    const int vf0   = (t >> 4) * 4;    // features vf0..vf0+3
#pragma unroll
    for (int c = 0; c < 4; ++c) {
        kreg[c] = kb4[(krow + 16 * c) * 16 + kcol4];
        vreg[c] = vb4[(vj0 + c) * 16 + (vf0 >> 2)];
    }

    for (int tile = 0; tile < ntiles; ++tile) {
        __syncthreads();   // prior tile's LDS readers done
#pragma unroll
        for (int c = 0; c < 4; ++c)    // K: raw f16 copy
            *(ushort4*)&ks[(krow + 16 * c) * KSTR + kcol4 * 4] = kreg[c];
        {                              // V: 4x4 in-register transpose
            ushort4 w0 = {vreg[0].x, vreg[1].x, vreg[2].x, vreg[3].x};
            ushort4 w1 = {vreg[0].y, vreg[1].y, vreg[2].y, vreg[3].y};
            ushort4 w2 = {vreg[0].z, vreg[1].z, vreg[2].z, vreg[3].z};
            ushort4 w3 = {vreg[0].w, vreg[1].w, vreg[2].w, vreg[3].w};
            *(ushort4*)&vt[(vf0 + 0) * KSTR + vj0] = w0;
            *(ushort4*)&vt[(vf0 + 1) * KSTR + vj0] = w1;
            *(ushort4*)&vt[(vf0 + 2) * KSTR + vj0] = w2;
            *(ushort4*)&vt[(vf0 + 3) * KSTR + vj0] = w3;
        }
        __syncthreads();   // staging visible

        if (tile + 1 < ntiles) {       // prefetch next tile (latency hidden by compute)
#pragma unroll
            for (int c = 0; c < 4; ++c) {
                kreg[c] = kb4[(tile + 1) * 1024 + (krow + 16 * c) * 16 + kcol4];
                vreg[c] = vb4[(tile + 1) * 1024 + (vj0 + c) * 16 + (vf0 >> 2)];
            }
        }

        // ---- QK^T: 4 key-subtiles x 2 d-chunks ----
        f32x4 S[4];
#pragma unroll
        for (int T = 0; T < 4; ++T) {
            const u16* kp = &ks[(16 * T + m15) * KSTR + quad * 8];
            half8 kb0 = *(const half8*)kp;
            half8 kb1 = *(const half8*)(kp + 32);
            S[T] = MFMAH(qa0, kb0, ((f32x4){0.f, 0.f, 0.f, 0.f}));
            S[T] = MFMAH(qa1, kb1, S[T]);
        }

        // ---- online softmax (rows 4*quad+r live in this quad) ----
        float mx[4], alpha[4], mn[4], psum[4];
#pragma unroll
        for (int T = 0; T < 4; ++T)
#pragma unroll
            for (int r = 0; r < 4; ++r) S[T][r] *= 0.125f;   // 1/sqrt(64)
#pragma unroll
        for (int r = 0; r < 4; ++r) {
            mx[r] = fmaxf(fmaxf(S[0][r], S[1][r]), fmaxf(S[2][r], S[3][r]));
#pragma unroll
            for (int s = 1; s < 16; s <<= 1) mx[r] = fmaxf(mx[r], __shfl_xor(mx[r], s));
            mn[r] = fmaxf(mrow[r], mx[r]);
            alpha[r] = __expf(mrow[r] - mn[r]);
            mrow[r] = mn[r];
            psum[r] = 0.f;
        }
#pragma unroll
        for (int T = 0; T < 4; ++T)
#pragma unroll
            for (int r = 0; r < 4; ++r) {
                float p = __expf(S[T][r] - mn[r]);
                psum[r] += p;
                ps[w][(4 * quad + r) * KSTR + 16 * T + m15] = f2h(p);
            }
#pragma unroll
        for (int r = 0; r < 4; ++r) {
#pragma unroll
            for (int s = 1; s < 16; s <<= 1) psum[r] += __shfl_xor(psum[r], s);
            lrow[r] = lrow[r] * alpha[r] + psum[r];
        }
#pragma unroll
        for (int F = 0; F < 4; ++F)
#pragma unroll
            for (int r = 0; r < 4; ++r) accO[F][r] *= alpha[r];

        // ---- PV: A = P (same-wave region, no barrier needed), B = Vt ----
        const u16* pp = &ps[w][m15 * KSTR + quad * 8];
        half8 pa0 = *(const half8*)pp;          // keys 0..31
        half8 pa1 = *(const half8*)(pp + 32);   // keys 32..63
#pragma unroll
        for (int F = 0; F < 4; ++F) {
            const u16* vp = &vt[(16 * F + m15) * KSTR + quad * 8];
            half8 vb0 = *(const half8*)vp;
            half8 vb1 = *(const half8*)(vp + 32);
            accO[F] = MFMAH(pa0, vb0, accO[F]);
            accO[F] = MFMAH(pa1, vb1, accO[F]);
        }
    }

    // ---- epilogue ----
    const long rowbase = (long)b * SEQ + q0 + 16 * w;
    if (norm) {
        float il[4];
#pragma unroll
        for (int r = 0; r < 4; ++r) il[r] = 1.f / lrow[r];
#pragma unroll
        for (int F = 0; F < 4; ++F)
#pragma unroll
            for (int r = 0; r < 4; ++r)
                Opart[(rowbase + 4 * quad + r) * DF + 16 * F + m15] = accO[F][r] * il[r];
    } else {
        float* Og = Opart + (size_t)z * (NB * SEQ * DF);
#pragma unroll
        for (int F = 0; F < 4; ++F)
#pragma unroll
            for (int r = 0; r < 4; ++r)
                Og[(rowbase + 4 * quad + r) * DF + 16 * F + m15] = accO[F][r];
        if (m15 == 0) {
#pragma unroll
            for (int r = 0; r < 4; ++r) {
                long rg = (long)z * (NB * SEQ) + rowbase + 4 * quad + r;
                Mp[rg] = mrow[r];
                Lp[rg] = lrow[r];
            }
        }
    }
}

// ---------------- combine: merge key-split flash partials -------------------
// out[row][f] = sum_g O_g[row][f] * e^{m_g - M} / (sum_g l_g * e^{m_g - M})
// 65536 threads: 4 threads/row, 16 features each.
__global__ __launch_bounds__(256) void combine_kernel(
    const float* __restrict__ Opart, const float* __restrict__ Mp, const float* __restrict__ Lp,
    float* __restrict__ out, int nsplit)
{
    const int tg  = blockIdx.x * 256 + threadIdx.x;
    const int row = tg >> 2;
    const int f0  = (tg & 3) * 16;

    float m = -1e30f;
    for (int g = 0; g < nsplit; ++g) m = fmaxf(m, Mp[g * (NB * SEQ) + row]);

    float l = 0.f;
    float4 o[4];
#pragma unroll
    for (int i = 0; i < 4; ++i) o[i] = (float4){0.f, 0.f, 0.f, 0.f};

    for (int g = 0; g < nsplit; ++g) {
        float e = __expf(Mp[g * (NB * SEQ) + row] - m);
        l += Lp[g * (NB * SEQ) + row] * e;
        const float* Op = Opart + ((long)g * (NB * SEQ) + row) * DF + f0;
#pragma unroll
        for (int i = 0; i < 4; ++i) {
            float4 v = *(const float4*)(Op + 4 * i);
            o[i].x += v.x * e; o[i].y += v.y * e; o[i].z += v.z * e; o[i].w += v.w * e;
        }
    }
    const float inv = 1.f / l;
#pragma unroll
    for (int i = 0; i < 4; ++i) {
        float4 v = {o[i].x * inv, o[i].y * inv, o[i].z * inv, o[i].w * inv};
        *(float4*)(out + (long)row * DF + f0 + 4 * i) = v;
    }
}

extern "C" void kernel_launch(void* const* d_in, const int* in_sizes, int n_in,
                              void* d_out, int out_size, void* d_ws, size_t ws_size,
                              hipStream_t stream) {
    (void)in_sizes; (void)n_in; (void)out_size;

    const float* X[3]  = { (const float*)d_in[0], (const float*)d_in[1], (const float*)d_in[2] };
    const float* W[3]  = { (const float*)d_in[3], (const float*)d_in[5], (const float*)d_in[7] };
    const float* Bv[3] = { (const float*)d_in[4], (const float*)d_in[6], (const float*)d_in[8] };

    char* wsb = (char*)d_ws;
    // workspace layout (bytes):
    const size_t P_BYTES  = (size_t)3 * NB * SEQ * DF * 2;   // 6,291,456  (Q,K,V f16)
    const size_t WH_BYTES = (size_t)3 * DF * DM * 2;         //   393,216  (Wh f16)
    const size_t ML_BYTES = (size_t)4 * NB * SEQ * 4;        //   262,144  (Mp / Lp each, max 4 splits)
    const size_t OP_BYTES = (size_t)NB * SEQ * DF * 4;       // 4,194,304  (per split)

    u16*   P   = (u16*)wsb;
    u16*   Wh  = (u16*)(wsb + P_BYTES);
    float* Mp  = (float*)(wsb + P_BYTES + WH_BYTES);
    float* Lp  = (float*)(wsb + P_BYTES + WH_BYTES + ML_BYTES);
    float* Op  = (float*)(wsb + P_BYTES + WH_BYTES + 2 * ML_BYTES);
    const size_t base_need = P_BYTES + WH_BYTES + 2 * ML_BYTES;

    int nsplit = 1;
    if (ws_size >= base_need + 4 * OP_BYTES)      nsplit = 4;
    else if (ws_size >= base_need + 2 * OP_BYTES) nsplit = 2;
    const int ntiles = (SEQ / 64) / nsplit;

    float* out = (float*)d_out;

    wprep_kernel<<<768, 256, 0, stream>>>(W[0], W[1], W[2], Wh);

    dim3 pgrid(NB * SEQ / 64, 3);
    proj6_kernel<<<pgrid, 512, 0, stream>>>(X[0], X[1], X[2], Wh,
                                            Bv[0], Bv[1], Bv[2], P);

    const size_t proj_elems = (size_t)NB * SEQ * DF;   // 1,048,576
    dim3 agrid(SEQ / 64, NB, nsplit);
    if (nsplit == 1) {
        attn_mfma_kernel<<<agrid, 256, 0, stream>>>(P, P + proj_elems, P + 2 * proj_elems,
                                                    out, Mp, Lp, ntiles, 1);
    } else {
        attn_mfma_kernel<<<agrid, 256, 0, stream>>>(P, P + proj_elems, P + 2 * proj_elems,
                                                    Op, Mp, Lp, ntiles, 0);
        combine_kernel<<<(NB * SEQ * 4) / 256, 256, 0, stream>>>(Op, Mp, Lp, out, nsplit);
    }
}